// Round 9
// baseline (98.040 us; speedup 1.0000x reference)
//
#include <hip/hip_runtime.h>
#include <hip/hip_bf16.h>

// ws layout: bf16 NHWC copies of the 4 feature levels (element offsets)
static constexpr size_t B3 = 0;
static constexpr size_t B4 = (size_t)4 * 256 * 16384;                 // after f3
static constexpr size_t B5 = B4 + (size_t)4 * 256 * 4096;             // after f4
static constexpr size_t B6 = B5 + (size_t)4 * 256 * 1024;             // after f5
static constexpr size_t WS_ELEMS = B6 + (size_t)4 * 256 * 256;        // bf16 elems

// ---------------- NCHW fp32 -> NHWC bf16 transpose -------------------------
__global__ __launch_bounds__(256) void transpose_nchw_nhwc_bf16(
    const float* __restrict__ f3, const float* __restrict__ f4,
    const float* __restrict__ f5, const float* __restrict__ f6,
    __hip_bfloat16* __restrict__ ws)
{
    __shared__ float tile[64][65];
    const int z   = blockIdx.z;         // lvl*4 + b
    const int lvl = z >> 2;
    const int b   = z & 3;
    const float* in; int H; size_t base;
    if      (lvl == 0) { in = f3; H = 128; base = B3; }
    else if (lvl == 1) { in = f4; H = 64;  base = B4; }
    else if (lvl == 2) { in = f5; H = 32;  base = B5; }
    else               { in = f6; H = 16;  base = B6; }
    const int HW  = H * H;
    const int hw0 = blockIdx.x * 64;
    if (hw0 >= HW) return;
    const int c0  = blockIdx.y * 64;
    const int tx  = threadIdx.x & 63;
    const int ty  = threadIdx.x >> 6;

    const float* inp = in + ((size_t)b * 256 + c0) * (size_t)HW + hw0;
    #pragma unroll
    for (int i = 0; i < 16; ++i) {
        const int cl = ty + 4 * i;
        tile[cl][tx] = inp[(size_t)cl * HW + tx];          // 256B/wave coalesced
    }
    __syncthreads();
    __hip_bfloat16* outp = ws + base + ((size_t)b * HW + hw0) * 256 + c0;
    #pragma unroll
    for (int i = 0; i < 16; ++i) {
        const int hl = ty + 4 * i;
        outp[(size_t)hl * 256 + tx] = __float2bfloat16(tile[tx][hl]);  // 128B/wave
    }
}

// ---------------- ROI gather from bf16 NHWC --------------------------------
// block = (ROI, 128-ch half); 256 threads; lane = 2 channels (uint load)
// Separable collapsed-tap tables: per output row/col, merge duplicate corner
// taps across the 2x2 subsamples (exact: weights factor & sum). Typical bin
// reads 4-9 positions instead of 16 -> fewer cache-line touches (the binder).
// R8 crash fix: zero-fill all table slots before compaction (unguarded ox0
// load must always be in-bounds; weight 0 kills its contribution).
__device__ __forceinline__ float bf_lo(unsigned u) { return __uint_as_float(u << 16); }
__device__ __forceinline__ float bf_hi(unsigned u) { return __uint_as_float(u & 0xffff0000u); }

__global__ __launch_bounds__(256) void roi_gather_nhwc_bf16(
    const unsigned* __restrict__ ws, const float* __restrict__ boxes,
    const int* __restrict__ img_ids, float* __restrict__ out)
{
    __shared__ __hip_bfloat16 lds[49][130];  // [bin][channel] staging, 12.7KB
    __shared__ int   yN[7];   __shared__ int   xN[7];
    __shared__ int   yPos[7][4]; __shared__ float yW[7][4];   // premul strides
    __shared__ int   xPos[7][4]; __shared__ float xW[7][4];

    const int n    = blockIdx.x;        // ROI
    const int c0   = blockIdx.y * 128;  // channel half
    const int t    = threadIdx.x;
    const int lane = t & 63;
    const int wv   = t >> 6;            // 0..3

    const float by = boxes[n * 4 + 0];
    const float bx = boxes[n * 4 + 1];
    const float bh = boxes[n * 4 + 2];
    const float bw = boxes[n * 4 + 3];

    float kf = floorf(4.0f + log2f(sqrtf(bh * bw) / 224.0f));
    kf = fminf(fmaxf(kf, 3.0f), 6.0f);
    const int lvl = (int)kf;

    int H; size_t base;
    if      (lvl == 3) { H = 128; base = B3; }
    else if (lvl == 4) { H = 64;  base = B4; }
    else if (lvl == 5) { H = 32;  base = B5; }
    else               { H = 16;  base = B6; }
    const float inv_stride = 1.0f / (float)(1 << lvl);
    const float Hf = (float)H;

    // tlbr/stride with the reference's swapped axis semantics (rounds 1-7 verified)
    const float tY = (by - bh * 0.5f) * inv_stride;
    const float lX = (bx - bw * 0.5f) * inv_stride;
    const float bY = (by + bh * 0.5f) * inv_stride;
    const float rX = (bx + bw * 0.5f) * inv_stride;
    const float binA = fmaxf(bY - tY, 1.0f) * (1.0f / 7.0f);  // col direction
    const float binB = fmaxf(rX - lX, 1.0f) * (1.0f / 7.0f);  // row direction

    // collapsed tap tables: wave0 -> 7 row tables, wave1 -> 7 col tables
    if (lane < 7 && wv < 2) {
        const int i = lane;
        // candidates from subsamples s=0,1: (lo, 1-fr), (hi, fr); invalid -> 0
        int   p_[4]; float w_[4];
        #pragma unroll
        for (int s = 0; s < 2; ++s) {
            const float off = (float)i + 0.25f + 0.5f * (float)s;
            const float coord = (wv == 0) ? (lX + off * binB) : (tY + off * binA);
            const bool v = (coord >= -1.0f) && (coord <= Hf);
            const float c = fminf(fmaxf(coord, 0.0f), Hf - 1.0f);
            const int lo = (int)c;
            const int hi = min(lo + 1, H - 1);
            const float fr = c - (float)lo;
            p_[2 * s]     = lo; w_[2 * s]     = v ? 1.0f - fr : 0.0f;
            p_[2 * s + 1] = hi; w_[2 * s + 1] = v ? fr : 0.0f;
        }
        // static dedup (merge equal positions; exact by separability)
        if (p_[1] == p_[0]) { w_[0] += w_[1]; w_[1] = 0.0f; }
        if (p_[2] == p_[0]) { w_[0] += w_[2]; w_[2] = 0.0f; }
        else if (p_[2] == p_[1]) { w_[1] += w_[2]; w_[2] = 0.0f; }
        if (p_[3] == p_[0]) { w_[0] += w_[3]; w_[3] = 0.0f; }
        else if (p_[3] == p_[1]) { w_[1] += w_[3]; w_[3] = 0.0f; }
        else if (p_[3] == p_[2]) { w_[2] += w_[3]; w_[3] = 0.0f; }
        // zero-fill ALL slots first (R8 fix), then compact nonzero taps
        const int mul = (wv == 0) ? H * 128 : 128;
        int cnt = 0;
        if (wv == 0) {
            #pragma unroll
            for (int q = 0; q < 4; ++q) { yPos[i][q] = 0; yW[i][q] = 0.0f; }
            #pragma unroll
            for (int q = 0; q < 4; ++q)
                if (w_[q] != 0.0f) { yPos[i][cnt] = p_[q] * mul; yW[i][cnt] = w_[q]; ++cnt; }
            yN[i] = cnt;
        } else {
            #pragma unroll
            for (int q = 0; q < 4; ++q) { xPos[i][q] = 0; xW[i][q] = 0.0f; }
            #pragma unroll
            for (int q = 0; q < 4; ++q)
                if (w_[q] != 0.0f) { xPos[i][cnt] = p_[q] * mul; xW[i][cnt] = w_[q]; ++cnt; }
            xN[i] = cnt;
        }
    }
    __syncthreads();

    const int img = img_ids[n];
    // uint units: 2 bf16 channels each; lane covers channels 2*lane, 2*lane+1
    const unsigned* fb = ws + (base >> 1) + (size_t)img * (size_t)(H * H) * 128
                       + (size_t)(c0 >> 1) + lane;

    for (int p = wv; p < 49; p += 4) {
        const int i = p / 7, j = p % 7;
        const int ny = yN[i];
        const int nx = xN[j];
        // hoist col table for this bin (uniform values; slots >= nx are {0,0})
        const int   ox0 = xPos[j][0], ox1 = xPos[j][1], ox2 = xPos[j][2], ox3 = xPos[j][3];
        const float xw0 = xW[j][0],   xw1 = xW[j][1],   xw2 = xW[j][2],   xw3 = xW[j][3];
        float accx = 0.0f, accy = 0.0f;
        #pragma unroll
        for (int a = 0; a < 4; ++a) {
            if (a < ny) {                                   // wave-uniform guard
                const float wy = yW[i][a];
                const int   oy = yPos[i][a];
                {
                    const unsigned u = fb[oy + ox0];        // safe: ox0 in-bounds always
                    const float w = wy * xw0;
                    accx += w * bf_lo(u); accy += w * bf_hi(u);
                }
                if (1 < nx) {
                    const unsigned u = fb[oy + ox1];
                    const float w = wy * xw1;
                    accx += w * bf_lo(u); accy += w * bf_hi(u);
                }
                if (2 < nx) {
                    const unsigned u = fb[oy + ox2];
                    const float w = wy * xw2;
                    accx += w * bf_lo(u); accy += w * bf_hi(u);
                }
                if (3 < nx) {
                    const unsigned u = fb[oy + ox3];
                    const float w = wy * xw3;
                    accx += w * bf_lo(u); accy += w * bf_hi(u);
                }
            }
        }
        // nx==0 or ny==0 -> acc stays 0 (matches reference's zeroed weights)
        lds[p][2 * lane]     = __float2bfloat16(accx * 0.25f);
        lds[p][2 * lane + 1] = __float2bfloat16(accy * 0.25f);
    }
    __syncthreads();

    // coalesced NCHW write-out: lanes = bins (49 active), wave w -> channels 32w..
    float* op = out + ((size_t)n * 256 + c0) * 49;
    if (lane < 49) {
        #pragma unroll 4
        for (int k = 0; k < 32; ++k) {
            const int c = wv * 32 + k;
            op[(size_t)c * 49 + lane] = __bfloat162float(lds[lane][c]);
        }
    }
}

// ---------------- fallback (round-1, direct NCHW gather) -------------------
__global__ __launch_bounds__(256) void roi_align_fallback(
    const float* __restrict__ f3, const float* __restrict__ f4,
    const float* __restrict__ f5, const float* __restrict__ f6,
    const float* __restrict__ boxes, const int* __restrict__ img_ids,
    float* __restrict__ out)
{
    const int n  = blockIdx.x;
    const int cg = blockIdx.y;
    const int t  = threadIdx.x;

    const float by = boxes[n * 4 + 0];
    const float bx = boxes[n * 4 + 1];
    const float bh = boxes[n * 4 + 2];
    const float bw = boxes[n * 4 + 3];

    float kf = floorf(4.0f + log2f(sqrtf(bh * bw) / 224.0f));
    kf = fminf(fmaxf(kf, 3.0f), 6.0f);
    const int lvl = (int)kf;

    const float* feat;
    int H;
    if      (lvl == 3) { feat = f3; H = 128; }
    else if (lvl == 4) { feat = f4; H = 64;  }
    else if (lvl == 5) { feat = f5; H = 32;  }
    else               { feat = f6; H = 16;  }

    const float inv_stride = 1.0f / (float)(1 << lvl);
    const float tY = (by - bh * 0.5f) * inv_stride;
    const float lX = (bx - bw * 0.5f) * inv_stride;
    const float bY = (by + bh * 0.5f) * inv_stride;
    const float rX = (bx + bw * 0.5f) * inv_stride;
    const float binA = fmaxf(bY - tY, 1.0f) / 7.0f;
    const float binB = fmaxf(rX - lX, 1.0f) / 7.0f;

    const int p   = t >> 2;
    const int s1  = (t >> 1) & 1;
    const int s2  = t & 1;
    const int ii  = p / 7;
    const int jj  = p % 7;
    const bool active = (t < 196);

    const float rc = lX + ((float)ii + ((float)s1 + 0.5f) * 0.5f) * binB;
    const float cc = tY + ((float)jj + ((float)s2 + 0.5f) * 0.5f) * binA;
    const float Hf = (float)H;
    const bool valid = active && (rc >= -1.0f) && (rc <= Hf) &&
                       (cc >= -1.0f) && (cc <= Hf);

    const float yc = fminf(fmaxf(rc, 0.0f), Hf - 1.0f);
    const float xc = fminf(fmaxf(cc, 0.0f), Hf - 1.0f);
    int yl = (int)floorf(yc);
    int xl = (int)floorf(xc);
    int yh = min(yl + 1, H - 1);
    int xh = min(xl + 1, H - 1);
    const float ly = yc - (float)yl;
    const float lx = xc - (float)xl;
    const float hy = 1.0f - ly;
    const float hx = 1.0f - lx;
    float w00 = hy * hx, w01 = hy * lx, w10 = ly * hx, w11 = ly * lx;
    if (!valid) { w00 = w01 = w10 = w11 = 0.0f; yl = xl = yh = xh = 0; }

    const int img = img_ids[n];
    const int HH  = H * H;
    const int c0  = cg * 64;
    const float* basep = feat + (size_t)(img * 256 + c0) * (size_t)HH;
    const int o00 = yl * H + xl, o01 = yl * H + xh;
    const int o10 = yh * H + xl, o11 = yh * H + xh;

    float* outp = out + ((size_t)n * 256 + c0) * 49 + p;
    #pragma unroll 4
    for (int c = 0; c < 64; ++c) {
        float v = w00 * basep[o00] + w01 * basep[o01]
                + w10 * basep[o10] + w11 * basep[o11];
        v += __shfl_xor(v, 1);
        v += __shfl_xor(v, 2);
        if (active && (t & 3) == 0) outp[(size_t)c * 49] = v * 0.25f;
        basep += HH;
    }
}

extern "C" void kernel_launch(void* const* d_in, const int* in_sizes, int n_in,
                              void* d_out, int out_size, void* d_ws, size_t ws_size,
                              hipStream_t stream)
{
    const float* f3      = (const float*)d_in[0];
    const float* f4      = (const float*)d_in[1];
    const float* f5      = (const float*)d_in[2];
    const float* f6      = (const float*)d_in[3];
    const float* boxes   = (const float*)d_in[4];
    const int*   img_ids = (const int*)d_in[5];
    float* outp          = (float*)d_out;
    const int N = in_sizes[5];                    // 1024 ROIs

    if (ws_size >= WS_ELEMS * sizeof(__hip_bfloat16)) {
        dim3 tgrid(256, 4, 16);                   // (hw tiles max, c tiles, lvl*4+b)
        transpose_nchw_nhwc_bf16<<<tgrid, 256, 0, stream>>>(
            f3, f4, f5, f6, (__hip_bfloat16*)d_ws);
        dim3 ggrid(N, 2);                         // (roi, ch half)
        roi_gather_nhwc_bf16<<<ggrid, 256, 0, stream>>>(
            (const unsigned*)d_ws, boxes, img_ids, outp);
    } else {
        dim3 grid(N, 4);
        roi_align_fallback<<<grid, 256, 0, stream>>>(f3, f4, f5, f6, boxes, img_ids, outp);
    }
}

// Round 10
// 58.057 us; speedup vs baseline: 1.6887x; 1.6887x over previous
//
#include <hip/hip_runtime.h>
#include <hip/hip_bf16.h>

// ws layout: bf16 NHWC copies of the 4 feature levels (element offsets)
static constexpr size_t B3 = 0;
static constexpr size_t B4 = (size_t)4 * 256 * 16384;                 // after f3
static constexpr size_t B5 = B4 + (size_t)4 * 256 * 4096;             // after f4
static constexpr size_t B6 = B5 + (size_t)4 * 256 * 1024;             // after f5
static constexpr size_t WS_ELEMS = B6 + (size_t)4 * 256 * 256;        // bf16 elems

// ---------------- NCHW fp32 -> NHWC bf16 transpose -------------------------
__global__ __launch_bounds__(256) void transpose_nchw_nhwc_bf16(
    const float* __restrict__ f3, const float* __restrict__ f4,
    const float* __restrict__ f5, const float* __restrict__ f6,
    __hip_bfloat16* __restrict__ ws)
{
    __shared__ float tile[64][65];
    const int z   = blockIdx.z;         // lvl*4 + b
    const int lvl = z >> 2;
    const int b   = z & 3;
    const float* in; int H; size_t base;
    if      (lvl == 0) { in = f3; H = 128; base = B3; }
    else if (lvl == 1) { in = f4; H = 64;  base = B4; }
    else if (lvl == 2) { in = f5; H = 32;  base = B5; }
    else               { in = f6; H = 16;  base = B6; }
    const int HW  = H * H;
    const int hw0 = blockIdx.x * 64;
    if (hw0 >= HW) return;
    const int c0  = blockIdx.y * 64;
    const int tx  = threadIdx.x & 63;
    const int ty  = threadIdx.x >> 6;

    const float* inp = in + ((size_t)b * 256 + c0) * (size_t)HW + hw0;
    #pragma unroll
    for (int i = 0; i < 16; ++i) {
        const int cl = ty + 4 * i;
        tile[cl][tx] = inp[(size_t)cl * HW + tx];          // 256B/wave coalesced
    }
    __syncthreads();
    __hip_bfloat16* outp = ws + base + ((size_t)b * HW + hw0) * 256 + c0;
    #pragma unroll
    for (int i = 0; i < 16; ++i) {
        const int hl = ty + 4 * i;
        outp[(size_t)hl * 256 + tx] = __float2bfloat16(tile[tx][hl]);  // 128B/wave
    }
}

// ---------------- ROI gather from bf16 NHWC --------------------------------
// Round-3 winner structure (best measured: 57.8us total, gather ~37us):
// block = (ROI, 128-ch half); 256 threads; lane = 2 channels (uint load);
// 16 unconditional independent corner loads per bin iteration (deep MLP);
// fp32 LDS staging [49][129]; single barrier; coalesced NCHW write-out.
// Tweak vs R3: the x0.25 subsample average is folded into the table weights
// (x0.5 per axis -> exact in fp32), removing one VALU op per LDS store.
__device__ __forceinline__ float bf_lo(unsigned u) { return __uint_as_float(u << 16); }
__device__ __forceinline__ float bf_hi(unsigned u) { return __uint_as_float(u & 0xffff0000u); }

__global__ __launch_bounds__(256) void roi_gather_nhwc_bf16(
    const unsigned* __restrict__ ws, const float* __restrict__ boxes,
    const int* __restrict__ img_ids, float* __restrict__ out)
{
    __shared__ float lds[49][129];      // [bin][channel] staging
    __shared__ float rW[14][2];         // {0.5*hy, 0.5*ly}  (zeroed if row-invalid)
    __shared__ int   rO[14][2];         // {yl, yh} * H * 128
    __shared__ float cW[14][2];         // {0.5*hx, 0.5*lx}  (zeroed if col-invalid)
    __shared__ int   cO[14][2];         // {xl, xh} * 128

    const int n    = blockIdx.x;        // ROI
    const int c0   = blockIdx.y * 128;  // channel half
    const int t    = threadIdx.x;
    const int lane = t & 63;
    const int wv   = t >> 6;            // 0..3

    const float by = boxes[n * 4 + 0];
    const float bx = boxes[n * 4 + 1];
    const float bh = boxes[n * 4 + 2];
    const float bw = boxes[n * 4 + 3];

    float kf = floorf(4.0f + log2f(sqrtf(bh * bw) / 224.0f));
    kf = fminf(fmaxf(kf, 3.0f), 6.0f);
    const int lvl = (int)kf;

    int H; size_t base;
    if      (lvl == 3) { H = 128; base = B3; }
    else if (lvl == 4) { H = 64;  base = B4; }
    else if (lvl == 5) { H = 32;  base = B5; }
    else               { H = 16;  base = B6; }
    const float inv_stride = 1.0f / (float)(1 << lvl);
    const float Hf = (float)H;

    // tlbr/stride with the reference's swapped axis semantics (rounds 1-9 verified)
    const float tY = (by - bh * 0.5f) * inv_stride;
    const float lX = (bx - bw * 0.5f) * inv_stride;
    const float bY = (by + bh * 0.5f) * inv_stride;
    const float rX = (bx + bw * 0.5f) * inv_stride;
    const float binA = fmaxf(bY - tY, 1.0f) * (1.0f / 7.0f);  // col direction
    const float binB = fmaxf(rX - lX, 1.0f) * (1.0f / 7.0f);  // row direction

    // separable sampling tables: 14 row coords (wave 0), 14 col coords (wave 1)
    // weights pre-scaled by 0.5 per axis so the product carries the 0.25 mean
    if (lane < 14 && wv < 2) {
        const int a = lane;
        const float off = (float)(a >> 1) + 0.25f + 0.5f * (float)(a & 1);
        if (wv == 0) {
            const float rc = lX + off * binB;
            const bool v = (rc >= -1.0f) && (rc <= Hf);
            const float yc = fminf(fmaxf(rc, 0.0f), Hf - 1.0f);
            const int yl = (int)yc;
            const int yh = min(yl + 1, H - 1);
            const float ly = yc - (float)yl;
            rW[a][0] = v ? 0.5f * (1.0f - ly) : 0.0f;
            rW[a][1] = v ? 0.5f * ly : 0.0f;
            rO[a][0] = yl * H * 128;
            rO[a][1] = yh * H * 128;
        } else {
            const float cc = tY + off * binA;
            const bool v = (cc >= -1.0f) && (cc <= Hf);
            const float xc = fminf(fmaxf(cc, 0.0f), Hf - 1.0f);
            const int xl = (int)xc;
            const int xh = min(xl + 1, H - 1);
            const float lx = xc - (float)xl;
            cW[a][0] = v ? 0.5f * (1.0f - lx) : 0.0f;
            cW[a][1] = v ? 0.5f * lx : 0.0f;
            cO[a][0] = xl * 128;
            cO[a][1] = xh * 128;
        }
    }
    __syncthreads();

    const int img = img_ids[n];
    // uint units: 2 bf16 channels each; lane covers channels 2*lane, 2*lane+1
    const unsigned* fb = ws + (base >> 1) + (size_t)img * (size_t)(H * H) * 128
                       + (size_t)(c0 >> 1) + lane;

    for (int p = wv; p < 49; p += 4) {
        const int a0 = (p / 7) * 2;
        const int b0 = (p % 7) * 2;
        float accx = 0.0f, accy = 0.0f;
        #pragma unroll
        for (int s1 = 0; s1 < 2; ++s1) {
            const float hy = rW[a0 + s1][0], lyw = rW[a0 + s1][1];
            const int oy0 = rO[a0 + s1][0], oy1 = rO[a0 + s1][1];
            #pragma unroll
            for (int s2 = 0; s2 < 2; ++s2) {
                const float hx = cW[b0 + s2][0], lxw = cW[b0 + s2][1];
                const int ox0 = cO[b0 + s2][0], ox1 = cO[b0 + s2][1];
                const unsigned u00 = fb[oy0 + ox0];
                const unsigned u01 = fb[oy0 + ox1];
                const unsigned u10 = fb[oy1 + ox0];
                const unsigned u11 = fb[oy1 + ox1];
                const float w00 = hy * hx, w01 = hy * lxw;
                const float w10 = lyw * hx, w11 = lyw * lxw;
                accx += w00 * bf_lo(u00) + w01 * bf_lo(u01)
                      + w10 * bf_lo(u10) + w11 * bf_lo(u11);
                accy += w00 * bf_hi(u00) + w01 * bf_hi(u01)
                      + w10 * bf_hi(u10) + w11 * bf_hi(u11);
            }
        }
        lds[p][2 * lane]     = accx;    // 0.25 already folded into weights
        lds[p][2 * lane + 1] = accy;
    }
    __syncthreads();

    // coalesced NCHW write-out: lanes = bins (49 active), wave w -> channels 32w..
    float* op = out + ((size_t)n * 256 + c0) * 49;
    if (lane < 49) {
        #pragma unroll 4
        for (int k = 0; k < 32; ++k) {
            const int c = wv * 32 + k;
            op[(size_t)c * 49 + lane] = lds[lane][c];
        }
    }
}

// ---------------- fallback (round-1, direct NCHW gather) -------------------
__global__ __launch_bounds__(256) void roi_align_fallback(
    const float* __restrict__ f3, const float* __restrict__ f4,
    const float* __restrict__ f5, const float* __restrict__ f6,
    const float* __restrict__ boxes, const int* __restrict__ img_ids,
    float* __restrict__ out)
{
    const int n  = blockIdx.x;
    const int cg = blockIdx.y;
    const int t  = threadIdx.x;

    const float by = boxes[n * 4 + 0];
    const float bx = boxes[n * 4 + 1];
    const float bh = boxes[n * 4 + 2];
    const float bw = boxes[n * 4 + 3];

    float kf = floorf(4.0f + log2f(sqrtf(bh * bw) / 224.0f));
    kf = fminf(fmaxf(kf, 3.0f), 6.0f);
    const int lvl = (int)kf;

    const float* feat;
    int H;
    if      (lvl == 3) { feat = f3; H = 128; }
    else if (lvl == 4) { feat = f4; H = 64;  }
    else if (lvl == 5) { feat = f5; H = 32;  }
    else               { feat = f6; H = 16;  }

    const float inv_stride = 1.0f / (float)(1 << lvl);
    const float tY = (by - bh * 0.5f) * inv_stride;
    const float lX = (bx - bw * 0.5f) * inv_stride;
    const float bY = (by + bh * 0.5f) * inv_stride;
    const float rX = (bx + bw * 0.5f) * inv_stride;
    const float binA = fmaxf(bY - tY, 1.0f) / 7.0f;
    const float binB = fmaxf(rX - lX, 1.0f) / 7.0f;

    const int p   = t >> 2;
    const int s1  = (t >> 1) & 1;
    const int s2  = t & 1;
    const int ii  = p / 7;
    const int jj  = p % 7;
    const bool active = (t < 196);

    const float rc = lX + ((float)ii + ((float)s1 + 0.5f) * 0.5f) * binB;
    const float cc = tY + ((float)jj + ((float)s2 + 0.5f) * 0.5f) * binA;
    const float Hf = (float)H;
    const bool valid = active && (rc >= -1.0f) && (rc <= Hf) &&
                       (cc >= -1.0f) && (cc <= Hf);

    const float yc = fminf(fmaxf(rc, 0.0f), Hf - 1.0f);
    const float xc = fminf(fmaxf(cc, 0.0f), Hf - 1.0f);
    int yl = (int)floorf(yc);
    int xl = (int)floorf(xc);
    int yh = min(yl + 1, H - 1);
    int xh = min(xl + 1, H - 1);
    const float ly = yc - (float)yl;
    const float lx = xc - (float)xl;
    const float hy = 1.0f - ly;
    const float hx = 1.0f - lx;
    float w00 = hy * hx, w01 = hy * lx, w10 = ly * hx, w11 = ly * lx;
    if (!valid) { w00 = w01 = w10 = w11 = 0.0f; yl = xl = yh = xh = 0; }

    const int img = img_ids[n];
    const int HH  = H * H;
    const int c0  = cg * 64;
    const float* basep = feat + (size_t)(img * 256 + c0) * (size_t)HH;
    const int o00 = yl * H + xl, o01 = yl * H + xh;
    const int o10 = yh * H + xl, o11 = yh * H + xh;

    float* outp = out + ((size_t)n * 256 + c0) * 49 + p;
    #pragma unroll 4
    for (int c = 0; c < 64; ++c) {
        float v = w00 * basep[o00] + w01 * basep[o01]
                + w10 * basep[o10] + w11 * basep[o11];
        v += __shfl_xor(v, 1);
        v += __shfl_xor(v, 2);
        if (active && (t & 3) == 0) outp[(size_t)c * 49] = v * 0.25f;
        basep += HH;
    }
}

extern "C" void kernel_launch(void* const* d_in, const int* in_sizes, int n_in,
                              void* d_out, int out_size, void* d_ws, size_t ws_size,
                              hipStream_t stream)
{
    const float* f3      = (const float*)d_in[0];
    const float* f4      = (const float*)d_in[1];
    const float* f5      = (const float*)d_in[2];
    const float* f6      = (const float*)d_in[3];
    const float* boxes   = (const float*)d_in[4];
    const int*   img_ids = (const int*)d_in[5];
    float* outp          = (float*)d_out;
    const int N = in_sizes[5];                    // 1024 ROIs

    if (ws_size >= WS_ELEMS * sizeof(__hip_bfloat16)) {
        dim3 tgrid(256, 4, 16);                   // (hw tiles max, c tiles, lvl*4+b)
        transpose_nchw_nhwc_bf16<<<tgrid, 256, 0, stream>>>(
            f3, f4, f5, f6, (__hip_bfloat16*)d_ws);
        dim3 ggrid(N, 2);                         // (roi, ch half)
        roi_gather_nhwc_bf16<<<ggrid, 256, 0, stream>>>(
            (const unsigned*)d_ws, boxes, img_ids, outp);
    } else {
        dim3 grid(N, 4);
        roi_align_fallback<<<grid, 256, 0, stream>>>(f3, f4, f5, f6, boxes, img_ids, outp);
    }
}

// Round 11
// 57.621 us; speedup vs baseline: 1.7015x; 1.0076x over previous
//
#include <hip/hip_runtime.h>
#include <hip/hip_bf16.h>

// ws layout: bf16 NHWC copies of the 4 feature levels (element offsets)
static constexpr size_t B3 = 0;
static constexpr size_t B4 = (size_t)4 * 256 * 16384;                 // after f3
static constexpr size_t B5 = B4 + (size_t)4 * 256 * 4096;             // after f4
static constexpr size_t B6 = B5 + (size_t)4 * 256 * 1024;             // after f5
static constexpr size_t WS_ELEMS = B6 + (size_t)4 * 256 * 256;        // bf16 elems

// ---------------- NCHW fp32 -> NHWC bf16 transpose -------------------------
__global__ __launch_bounds__(256) void transpose_nchw_nhwc_bf16(
    const float* __restrict__ f3, const float* __restrict__ f4,
    const float* __restrict__ f5, const float* __restrict__ f6,
    __hip_bfloat16* __restrict__ ws)
{
    __shared__ float tile[64][65];
    const int z   = blockIdx.z;         // lvl*4 + b
    const int lvl = z >> 2;
    const int b   = z & 3;
    const float* in; int H; size_t base;
    if      (lvl == 0) { in = f3; H = 128; base = B3; }
    else if (lvl == 1) { in = f4; H = 64;  base = B4; }
    else if (lvl == 2) { in = f5; H = 32;  base = B5; }
    else               { in = f6; H = 16;  base = B6; }
    const int HW  = H * H;
    const int hw0 = blockIdx.x * 64;
    if (hw0 >= HW) return;
    const int c0  = blockIdx.y * 64;
    const int tx  = threadIdx.x & 63;
    const int ty  = threadIdx.x >> 6;

    const float* inp = in + ((size_t)b * 256 + c0) * (size_t)HW + hw0;
    #pragma unroll
    for (int i = 0; i < 16; ++i) {
        const int cl = ty + 4 * i;
        tile[cl][tx] = inp[(size_t)cl * HW + tx];          // 256B/wave coalesced
    }
    __syncthreads();
    __hip_bfloat16* outp = ws + base + ((size_t)b * HW + hw0) * 256 + c0;
    #pragma unroll
    for (int i = 0; i < 16; ++i) {
        const int hl = ty + 4 * i;
        outp[(size_t)hl * 256 + tx] = __float2bfloat16(tile[tx][hl]);  // 128B/wave
    }
}

// ---------------- ROI gather, dwordx4 (address-reduction experiment) -------
// One block per ROI, 256 threads (4 waves). lane = (channel-group g = lane&31
// covering 8 channels via uint4 = 16B, corner-half b = lane>>5).
// Per subsample: 2 wave-loads fetch all 4 bilinear corners for ALL 256
// channels (1KB/wave-load, 8 full lines, only 64 addresses). Per bin:
// 8 wave-loads = 512 addresses, vs round-3's 2048. Same total bytes.
// Per-lane acc covers its column-side b; one shfl_xor(32) merges halves.
__device__ __forceinline__ float bf_lo(unsigned u) { return __uint_as_float(u << 16); }
__device__ __forceinline__ float bf_hi(unsigned u) { return __uint_as_float(u & 0xffff0000u); }
__device__ __forceinline__ unsigned short bfbits(float f) {
    __hip_bfloat16 h = __float2bfloat16(f);
    return *reinterpret_cast<unsigned short*>(&h);
}

__global__ __launch_bounds__(256) void roi_gather_x4(
    const uint4* __restrict__ ws4, const float* __restrict__ boxes,
    const int* __restrict__ img_ids, float* __restrict__ out)
{
    __shared__ __hip_bfloat16 lds[49][258];  // [bin][channel]; stride 129 dwords
                                             // -> conflict-free write-out reads
    __shared__ float rW[14][2];         // {0.5*hy, 0.5*ly}  (0 if row-invalid)
    __shared__ int   rO[14][2];         // {yl, yh} * H * 32   (uint4 units)
    __shared__ float cW[14][2];         // {0.5*hx, 0.5*lx}  (0 if col-invalid)
    __shared__ int   cO[14][2];         // {xl, xh} * 32

    const int n    = blockIdx.x;        // ROI
    const int t    = threadIdx.x;
    const int lane = t & 63;
    const int wv   = t >> 6;            // 0..3
    const int g    = lane & 31;         // channel group (8 ch)
    const int b    = lane >> 5;         // corner column half

    const float by = boxes[n * 4 + 0];
    const float bx = boxes[n * 4 + 1];
    const float bh = boxes[n * 4 + 2];
    const float bw = boxes[n * 4 + 3];

    float kf = floorf(4.0f + log2f(sqrtf(bh * bw) / 224.0f));
    kf = fminf(fmaxf(kf, 3.0f), 6.0f);
    const int lvl = (int)kf;

    int H; size_t base;
    if      (lvl == 3) { H = 128; base = B3; }
    else if (lvl == 4) { H = 64;  base = B4; }
    else if (lvl == 5) { H = 32;  base = B5; }
    else               { H = 16;  base = B6; }
    const float inv_stride = 1.0f / (float)(1 << lvl);
    const float Hf = (float)H;

    // tlbr/stride with the reference's swapped axis semantics (rounds 1-10)
    const float tY = (by - bh * 0.5f) * inv_stride;
    const float lX = (bx - bw * 0.5f) * inv_stride;
    const float bY = (by + bh * 0.5f) * inv_stride;
    const float rX = (bx + bw * 0.5f) * inv_stride;
    const float binA = fmaxf(bY - tY, 1.0f) * (1.0f / 7.0f);  // col direction
    const float binB = fmaxf(rX - lX, 1.0f) * (1.0f / 7.0f);  // row direction

    // separable tables; 0.25 mean folded as 0.5 per axis
    if (lane < 14 && wv < 2) {
        const int a = lane;
        const float off = (float)(a >> 1) + 0.25f + 0.5f * (float)(a & 1);
        if (wv == 0) {
            const float rc = lX + off * binB;
            const bool v = (rc >= -1.0f) && (rc <= Hf);
            const float yc = fminf(fmaxf(rc, 0.0f), Hf - 1.0f);
            const int yl = (int)yc;
            const int yh = min(yl + 1, H - 1);
            const float ly = yc - (float)yl;
            rW[a][0] = v ? 0.5f * (1.0f - ly) : 0.0f;
            rW[a][1] = v ? 0.5f * ly : 0.0f;
            rO[a][0] = yl * H * 32;
            rO[a][1] = yh * H * 32;
        } else {
            const float cc = tY + off * binA;
            const bool v = (cc >= -1.0f) && (cc <= Hf);
            const float xc = fminf(fmaxf(cc, 0.0f), Hf - 1.0f);
            const int xl = (int)xc;
            const int xh = min(xl + 1, H - 1);
            const float lx = xc - (float)xl;
            cW[a][0] = v ? 0.5f * (1.0f - lx) : 0.0f;
            cW[a][1] = v ? 0.5f * lx : 0.0f;
            cO[a][0] = xl * 32;
            cO[a][1] = xh * 32;
        }
    }
    __syncthreads();

    const int img = img_ids[n];
    // uint4 units: 8 bf16 channels each; pixel record = 32 uint4
    const uint4* fb = ws4 + (base >> 3)
                    + (size_t)img * (size_t)(H * H) * 32 + g;

    for (int p = wv; p < 49; p += 4) {
        const int a0 = (p / 7) * 2;
        const int b0 = (p % 7) * 2;
        float acc[8] = {0.f, 0.f, 0.f, 0.f, 0.f, 0.f, 0.f, 0.f};
        #pragma unroll
        for (int s = 0; s < 4; ++s) {
            const int s1 = s >> 1, s2 = s & 1;
            const int   oy0 = rO[a0 + s1][0], oy1 = rO[a0 + s1][1];
            const float wy0 = rW[a0 + s1][0], wy1 = rW[a0 + s1][1];
            const int   ox  = cO[b0 + s2][b];    // per-half column corner
            const float wx  = cW[b0 + s2][b];
            const uint4 vA = fb[oy0 + ox];       // 1KB/wave: 4 corners x 256ch
            const uint4 vB = fb[oy1 + ox];
            const float wA = wy0 * wx, wB = wy1 * wx;
            acc[0] += wA * bf_lo(vA.x) + wB * bf_lo(vB.x);
            acc[1] += wA * bf_hi(vA.x) + wB * bf_hi(vB.x);
            acc[2] += wA * bf_lo(vA.y) + wB * bf_lo(vB.y);
            acc[3] += wA * bf_hi(vA.y) + wB * bf_hi(vB.y);
            acc[4] += wA * bf_lo(vA.z) + wB * bf_lo(vB.z);
            acc[5] += wA * bf_hi(vA.z) + wB * bf_hi(vB.z);
            acc[6] += wA * bf_lo(vA.w) + wB * bf_lo(vB.w);
            acc[7] += wA * bf_hi(vA.w) + wB * bf_hi(vB.w);
        }
        // merge the two column-halves (channels identical per g)
        #pragma unroll
        for (int k = 0; k < 8; ++k) acc[k] += __shfl_xor(acc[k], 32);
        if (b == 0) {
            unsigned* dst = reinterpret_cast<unsigned*>(&lds[p][8 * g]);
            dst[0] = (unsigned)bfbits(acc[0]) | ((unsigned)bfbits(acc[1]) << 16);
            dst[1] = (unsigned)bfbits(acc[2]) | ((unsigned)bfbits(acc[3]) << 16);
            dst[2] = (unsigned)bfbits(acc[4]) | ((unsigned)bfbits(acc[5]) << 16);
            dst[3] = (unsigned)bfbits(acc[6]) | ((unsigned)bfbits(acc[7]) << 16);
        }
    }
    __syncthreads();

    // coalesced NCHW write-out: lanes = bins (49 active), wave w covers 64 ch
    float* op = out + (size_t)n * 256 * 49;
    if (lane < 49) {
        #pragma unroll 4
        for (int k = 0; k < 64; ++k) {
            const int c = wv * 64 + k;
            op[(size_t)c * 49 + lane] = __bfloat162float(lds[lane][c]);
        }
    }
}

// ---------------- fallback (round-1, direct NCHW gather) -------------------
__global__ __launch_bounds__(256) void roi_align_fallback(
    const float* __restrict__ f3, const float* __restrict__ f4,
    const float* __restrict__ f5, const float* __restrict__ f6,
    const float* __restrict__ boxes, const int* __restrict__ img_ids,
    float* __restrict__ out)
{
    const int n  = blockIdx.x;
    const int cg = blockIdx.y;
    const int t  = threadIdx.x;

    const float by = boxes[n * 4 + 0];
    const float bx = boxes[n * 4 + 1];
    const float bh = boxes[n * 4 + 2];
    const float bw = boxes[n * 4 + 3];

    float kf = floorf(4.0f + log2f(sqrtf(bh * bw) / 224.0f));
    kf = fminf(fmaxf(kf, 3.0f), 6.0f);
    const int lvl = (int)kf;

    const float* feat;
    int H;
    if      (lvl == 3) { feat = f3; H = 128; }
    else if (lvl == 4) { feat = f4; H = 64;  }
    else if (lvl == 5) { feat = f5; H = 32;  }
    else               { feat = f6; H = 16;  }

    const float inv_stride = 1.0f / (float)(1 << lvl);
    const float tY = (by - bh * 0.5f) * inv_stride;
    const float lX = (bx - bw * 0.5f) * inv_stride;
    const float bY = (by + bh * 0.5f) * inv_stride;
    const float rX = (bx + bw * 0.5f) * inv_stride;
    const float binA = fmaxf(bY - tY, 1.0f) / 7.0f;
    const float binB = fmaxf(rX - lX, 1.0f) / 7.0f;

    const int p   = t >> 2;
    const int s1  = (t >> 1) & 1;
    const int s2  = t & 1;
    const int ii  = p / 7;
    const int jj  = p % 7;
    const bool active = (t < 196);

    const float rc = lX + ((float)ii + ((float)s1 + 0.5f) * 0.5f) * binB;
    const float cc = tY + ((float)jj + ((float)s2 + 0.5f) * 0.5f) * binA;
    const float Hf = (float)H;
    const bool valid = active && (rc >= -1.0f) && (rc <= Hf) &&
                       (cc >= -1.0f) && (cc <= Hf);

    const float yc = fminf(fmaxf(rc, 0.0f), Hf - 1.0f);
    const float xc = fminf(fmaxf(cc, 0.0f), Hf - 1.0f);
    int yl = (int)floorf(yc);
    int xl = (int)floorf(xc);
    int yh = min(yl + 1, H - 1);
    int xh = min(xl + 1, H - 1);
    const float ly = yc - (float)yl;
    const float lx = xc - (float)xl;
    const float hy = 1.0f - ly;
    const float hx = 1.0f - lx;
    float w00 = hy * hx, w01 = hy * lx, w10 = ly * hx, w11 = ly * lx;
    if (!valid) { w00 = w01 = w10 = w11 = 0.0f; yl = xl = yh = xh = 0; }

    const int img = img_ids[n];
    const int HH  = H * H;
    const int c0  = cg * 64;
    const float* basep = feat + (size_t)(img * 256 + c0) * (size_t)HH;
    const int o00 = yl * H + xl, o01 = yl * H + xh;
    const int o10 = yh * H + xl, o11 = yh * H + xh;

    float* outp = out + ((size_t)n * 256 + c0) * 49 + p;
    #pragma unroll 4
    for (int c = 0; c < 64; ++c) {
        float v = w00 * basep[o00] + w01 * basep[o01]
                + w10 * basep[o10] + w11 * basep[o11];
        v += __shfl_xor(v, 1);
        v += __shfl_xor(v, 2);
        if (active && (t & 3) == 0) outp[(size_t)c * 49] = v * 0.25f;
        basep += HH;
    }
}

extern "C" void kernel_launch(void* const* d_in, const int* in_sizes, int n_in,
                              void* d_out, int out_size, void* d_ws, size_t ws_size,
                              hipStream_t stream)
{
    const float* f3      = (const float*)d_in[0];
    const float* f4      = (const float*)d_in[1];
    const float* f5      = (const float*)d_in[2];
    const float* f6      = (const float*)d_in[3];
    const float* boxes   = (const float*)d_in[4];
    const int*   img_ids = (const int*)d_in[5];
    float* outp          = (float*)d_out;
    const int N = in_sizes[5];                    // 1024 ROIs

    if (ws_size >= WS_ELEMS * sizeof(__hip_bfloat16)) {
        dim3 tgrid(256, 4, 16);                   // (hw tiles max, c tiles, lvl*4+b)
        transpose_nchw_nhwc_bf16<<<tgrid, 256, 0, stream>>>(
            f3, f4, f5, f6, (__hip_bfloat16*)d_ws);
        roi_gather_x4<<<N, 256, 0, stream>>>(
            (const uint4*)d_ws, boxes, img_ids, outp);
    } else {
        dim3 grid(N, 4);
        roi_align_fallback<<<grid, 256, 0, stream>>>(f3, f4, f5, f6, boxes, img_ids, outp);
    }
}